// Round 13
// baseline (845.230 us; speedup 1.0000x reference)
//
#include <hip/hip_runtime.h>
#include <hip/hip_bf16.h>

#define DEVINL __device__ __forceinline__

typedef __attribute__((ext_vector_type(8))) __bf16 bf16x8;
typedef __attribute__((ext_vector_type(16))) float f32x16;
typedef __attribute__((ext_vector_type(4))) unsigned short us4;

DEVINL unsigned short f2bf(float f) {
  union { float f; unsigned int u; } c;
  c.f = f;
  unsigned int u = c.u;
  u += 0x7fffu + ((u >> 16) & 1u);   // RNE
  return (unsigned short)(u >> 16);
}

// jax.nn.gelu(approximate=True) = x * sigmoid(2*sqrt(2/pi)*(x + 0.044715 x^3))
DEVINL float gelu_tanh(float x) {
  float t = 1.5957691216057308f * x * __builtin_fmaf(0.044715f, x * x, 1.0f);
  return x / (1.0f + __expf(-t));
}

DEVINL void ld16(const void* g, void* l) {
  __builtin_amdgcn_global_load_lds(
      (const __attribute__((address_space(1))) void*)g,
      (__attribute__((address_space(3))) void*)l, 16, 0, 0);
}

// ---------------- transpose + fp32->bf16 cast: in[R][C] f32 -> out[C][R] bf16
__global__ __launch_bounds__(256) void transpose_cast_kernel(
    const float* __restrict__ in, unsigned short* __restrict__ out, int R, int C) {
  __shared__ float tile[32][33];
  const int t = threadIdx.x;
  const int r0 = blockIdx.x << 5, c0 = blockIdx.y << 5;
  const int tr = t >> 3, tc = (t & 7) << 2;
  const float4 v = *(const float4*)(in + (size_t)(r0 + tr) * C + c0 + tc);
  tile[tr][tc] = v.x; tile[tr][tc + 1] = v.y;
  tile[tr][tc + 2] = v.z; tile[tr][tc + 3] = v.w;
  __syncthreads();
  us4 o;
  o[0] = f2bf(tile[tc + 0][tr]);
  o[1] = f2bf(tile[tc + 1][tr]);
  o[2] = f2bf(tile[tc + 2][tr]);
  o[3] = f2bf(tile[tc + 3][tr]);
  *(us4*)(out + (size_t)(c0 + tr) * R + r0 + tc) = o;
}

// ---------------- LayerNorm: x[8192][2048] f32 -> ln bf16
__global__ __launch_bounds__(256) void ln_kernel(
    const float* __restrict__ x, const float* __restrict__ gamma,
    const float* __restrict__ beta, unsigned short* __restrict__ out) {
  constexpr int H = 2048;
  const int t = threadIdx.x;
  const size_t row = blockIdx.x;
  const float4* xr = (const float4*)(x + row * H);
  const float4 a = xr[t], b = xr[t + 256];
  float s  = a.x + a.y + a.z + a.w + b.x + b.y + b.z + b.w;
  float s2 = a.x*a.x + a.y*a.y + a.z*a.z + a.w*a.w
           + b.x*b.x + b.y*b.y + b.z*b.z + b.w*b.w;
#pragma unroll
  for (int o = 32; o > 0; o >>= 1) { s += __shfl_xor(s, o); s2 += __shfl_xor(s2, o); }
  __shared__ float red[8];
  const int wid = t >> 6, lane = t & 63;
  if (lane == 0) { red[wid] = s; red[4 + wid] = s2; }
  __syncthreads();
  s  = red[0] + red[1] + red[2] + red[3];
  s2 = red[4] + red[5] + red[6] + red[7];
  const float mean = s * (1.0f / H);
  const float rstd = rsqrtf(s2 * (1.0f / H) - mean * mean + 1e-6f);
  const float4 g0 = ((const float4*)gamma)[t], g1 = ((const float4*)gamma)[t + 256];
  const float4 c0 = ((const float4*)beta)[t],  c1 = ((const float4*)beta)[t + 256];
  us4 o0, o1;
  o0[0] = f2bf((a.x - mean) * rstd * g0.x + c0.x);
  o0[1] = f2bf((a.y - mean) * rstd * g0.y + c0.y);
  o0[2] = f2bf((a.z - mean) * rstd * g0.z + c0.z);
  o0[3] = f2bf((a.w - mean) * rstd * g0.w + c0.w);
  o1[0] = f2bf((b.x - mean) * rstd * g1.x + c1.x);
  o1[1] = f2bf((b.y - mean) * rstd * g1.y + c1.y);
  o1[2] = f2bf((b.z - mean) * rstd * g1.z + c1.z);
  o1[3] = f2bf((b.w - mean) * rstd * g1.w + c1.w);
  *(us4*)(out + row * H + (size_t)t * 4) = o0;
  *(us4*)(out + row * H + 1024 + (size_t)t * 4) = o1;
}

// ---------------- 256-wide MFMA GEMM with 32x32x16 matrix cores (r9 skeleton)
// A [*][KDIM] bf16 K-contig. Bm0/Bm1: B^T row panels (K-contig).
// GATED: block tile = 256x128, two B mats (gelu(y0)*y1 -> bf16 Z[*,8192])
// else : block tile = 256x256, Bm1 = Bm0 + 128 rows (f32 Out[*,2048])
// LDS slots/buffer: A-lo | A-hi | B0 | B1 (16K each); double buffered = 128KB —
// staging geometry and swizzle byte-identical to the verified 16x16 kernel.
// MFMA shape 32x32x16 (m119: 2495 TF vs 2176 for 16x16, +14.7%; half the
// instruction count). Per wave: rows = mh*128 + wr*64 + mm*32 + (l&31),
// cols = wc*32 + (l&31); A/B frag: k = (l>>5)*8+j -> chunk = (2ks+l5)^(row&7)
// (same swizzle algebra); C/D: col=l&31, row=(r&3)+8*(r>>2)+4*(l>>5) [m74/m101].
// K-tile t (r9 flow, 2 barriers): TOP {LGKM(0); stage A-hi/B1(t+1);
// SUPER(0)=16 MFMA; read af_hi; LGKM(0); BAR_B}; MID {stage A-lo/B0(t+2);
// vmcnt(4); BAR_A}; TAIL {per-mm: 8 MFMA then read af_lo[.,mm](t+1) (WAR-safe);
// then b0/b1(t+1) reads}. Hazard + vmcnt ledger identical to r9 (verified).
template<int KDIM, bool GATED>
__global__ __launch_bounds__(512, 2) void gemm32(
    const unsigned short* __restrict__ Amat,
    const unsigned short* __restrict__ Bm0,
    const unsigned short* __restrict__ Bm1,
    void* __restrict__ outp, int mCount) {
  constexpr int NT = KDIM / 64;
  __shared__ char lds[131072];
  const int t = threadIdx.x, lane = t & 63, wid = t >> 6;
  const int wr = wid >> 2, wc = wid & 3;                // 2 x 4 waves
  const int bid = (int)blockIdx.x;
  int mb, nb;
  if (GATED && mCount >= 8) {
    // L2-lockstep 2D chunk map: per XCD, 32 concurrent blocks = 8 mb x 4 nb.
    const int xcd = bid & 7, l = bid >> 3;
    const int g = l >> 5, l32 = l & 31;
    const int mchunks = mCount >> 3;
    const int quad = g / mchunks, mch = g % mchunks;
    mb = (mch << 3) | (l32 & 7);
    nb = (xcd << 3) | (quad << 2) | (l32 >> 3);
  } else {
    // gemm2: one nb per XCD (B panel 4MB L2-resident)
    const int nwg = (int)gridDim.x, q = nwg >> 3;
    const int wg = (bid & 7) * q + (bid >> 3);
    mb = wg % mCount; nb = wg / mCount;
  }
  const size_t m0 = (size_t)mb << 8;
  const size_t nrow = (size_t)nb * (GATED ? 128 : 256);
  const unsigned short* aSrc  = Amat + m0 * KDIM;
  const unsigned short* b0Src = Bm0 + nrow * KDIM;
  const unsigned short* b1Src = Bm1 + nrow * KDIM;

  // staging geometry: unit = 128 rows x 64 k x 2B = 16KB = 2 x ld16/thread
  const int srow = (wid << 3) + (lane >> 3);            // 0..63
  const int sOff = srow * KDIM + (((lane & 7) ^ (srow & 7)) << 3);  // pre-swizzled source

  // 32x32 fragment geometry
  const int l31 = lane & 31, l5 = lane >> 5;
  int chunkOff[4];
#pragma unroll
  for (int ks = 0; ks < 4; ++ks)
    chunkOff[ks] = (((ks << 1) + l5) ^ (l31 & 7)) << 4;  // swizzled 16B chunk
  const int rowA0 = ((wr << 6) + l31) << 7;              // mm=0 row byte-off
  const int rowA1 = ((wr << 6) + 32 + l31) << 7;         // mm=1
  const int rowB  = ((wc << 5) + l31) << 7;

  f32x16 acc[2][2][2] = {};                              // [mh][g][mm]

  auto stageU = [&](const unsigned short* src, int ldsOff, int k0) {
    const unsigned short* s = src + sOff + k0;
    ld16(s, lds + ldsOff + (wid << 10));
    ld16(s + (size_t)64 * KDIM, lds + ldsOff + 8192 + (wid << 10));
  };

#define RD_AF_MM(ab_, mm_)                                                    \
  _Pragma("unroll") for (int ks = 0; ks < 4; ++ks)                            \
    af[ks][mm_] = *(const bf16x8*)((ab_) + ((mm_) ? rowA1 : rowA0) + chunkOff[ks]);
#define READ_AF(ab_) { RD_AF_MM(ab_, 0) RD_AF_MM(ab_, 1) }
#define READ_B(dst_, bb_)                                                     \
  _Pragma("unroll") for (int ks = 0; ks < 4; ++ks)                            \
    dst_[ks] = *(const bf16x8*)((bb_) + rowB + chunkOff[ks]);
// SUPER cluster: 16 MFMA for one mh; order ks->mm->g gives chain distance 4
#define MFMA_SUPER(mh_)                                                       \
  _Pragma("unroll") for (int ks = 0; ks < 4; ++ks)                            \
    _Pragma("unroll") for (int mm = 0; mm < 2; ++mm) {                        \
      acc[mh_][0][mm] = __builtin_amdgcn_mfma_f32_32x32x16_bf16(              \
          af[ks][mm], b0r[ks], acc[mh_][0][mm], 0, 0, 0);                     \
      acc[mh_][1][mm] = __builtin_amdgcn_mfma_f32_32x32x16_bf16(              \
          af[ks][mm], b1r[ks], acc[mh_][1][mm], 0, 0, 0);                     \
    }
// per-mm group of mh=1 (8 MFMA), used in TAIL so af[.,mm] can be re-read after
#define MFMA_MM(mh_, mm_)                                                     \
  _Pragma("unroll") for (int ks = 0; ks < 4; ++ks) {                          \
    acc[mh_][0][mm_] = __builtin_amdgcn_mfma_f32_32x32x16_bf16(               \
        af[ks][mm_], b0r[ks], acc[mh_][0][mm_], 0, 0, 0);                     \
    acc[mh_][1][mm_] = __builtin_amdgcn_mfma_f32_32x32x16_bf16(               \
        af[ks][mm_], b1r[ks], acc[mh_][1][mm_], 0, 0, 0);                     \
  }
#define LGKM(n_)                                                              \
  asm volatile("s_waitcnt lgkmcnt(" #n_ ")" ::: "memory");                    \
  __builtin_amdgcn_sched_barrier(0);
#define SCHED0 __builtin_amdgcn_sched_barrier(0)

  // prologue: tile0 (A-lo,B0,A-hi,B1) + tile1 (A-lo,B0); wait tile0 landed
  stageU(aSrc, 0, 0);
  stageU(b0Src, 32768, 0);
  stageU(aSrc + (size_t)128 * KDIM, 16384, 0);
  stageU(b1Src, 49152, 0);
  stageU(aSrc, 65536, NT > 1 ? 64 : 0);
  stageU(b0Src, 65536 + 32768, NT > 1 ? 64 : 0);
  asm volatile("s_waitcnt vmcnt(4)" ::: "memory");   // tile0's 8 loads retired
  __builtin_amdgcn_s_barrier();

  bf16x8 af[4][2], b0r[4], b1r[4];
  // initial reads for tile 0 (same order as steady-state tail)
  READ_AF(lds);              SCHED0;
  READ_B(b0r, lds + 32768);  SCHED0;
  READ_B(b1r, lds + 49152);  SCHED0;

  for (int tt = 0; tt < NT; ++tt) {
    const int c = tt & 1, cn = c ^ 1;
    const int t1 = (tt + 1 < NT) ? tt + 1 : NT - 1;
    const int t2 = (tt + 2 < NT) ? tt + 2 : NT - 1;
    const int k1b = t1 << 6, k2b = t2 << 6;
    const int cb = c << 16, cnb = cn << 16;
    const char* base = lds + cb;
    const char* nbase = lds + cnb;

    // ---- TOP
    stageU(aSrc + (size_t)128 * KDIM, cnb + 16384, k1b);  // A-hi(t+1)
    stageU(b1Src, cnb + 49152, k1b);                      // B1(t+1)
    LGKM(0);                                    // tail reads of t in regs
    __builtin_amdgcn_s_setprio(1);
    MFMA_SUPER(0);                              // af_lo x {b0r,b1r}
    __builtin_amdgcn_s_setprio(0);
    SCHED0;
    READ_AF(base + 16384);                      // af_hi(t), WAR after SUPER(0)
    LGKM(0);                                    // af_hi drained
    __builtin_amdgcn_s_barrier();               // BAR_B

    // ---- MID
    stageU(aSrc, cb, k2b);                      // A-lo(t+2)
    stageU(b0Src, cb + 32768, k2b);             // B0(t+2)
    asm volatile("s_waitcnt vmcnt(4)" ::: "memory");  // tile t+1 fully landed
    SCHED0;
    __builtin_amdgcn_s_barrier();               // BAR_A — t+1 visible to all

    // ---- TAIL: mh=1 MFMAs with af_lo(t+1) reads at per-mm death points
    __builtin_amdgcn_s_setprio(1);
    MFMA_MM(1, 0);                              // af[.,0] dead
    RD_AF_MM(nbase, 0) SCHED0;                  // af_lo[.,0](t+1)
    MFMA_MM(1, 1);                              // af[.,1] dead
    RD_AF_MM(nbase, 1) SCHED0;                  // af_lo[.,1](t+1)
    __builtin_amdgcn_s_setprio(0);
    READ_B(b0r, nbase + 32768); SCHED0;         // b0(t+1); b0r dead
    READ_B(b1r, nbase + 49152); SCHED0;         // b1(t+1); b1r dead
  }
  asm volatile("s_waitcnt vmcnt(0) lgkmcnt(0)" ::: "memory");  // drain tail
#undef RD_AF_MM
#undef READ_AF
#undef READ_B
#undef MFMA_SUPER
#undef MFMA_MM
#undef LGKM
#undef SCHED0

  // epilogue: C/D 32x32 layout col=l&31, row=(r&3)+8*(r>>2)+4*(l>>5)
  if constexpr (GATED) {
    unsigned short* Z = (unsigned short*)outp;        // [*, 8192]
#pragma unroll
    for (int mh = 0; mh < 2; ++mh)
#pragma unroll
      for (int mm = 0; mm < 2; ++mm) {
        const size_t rb = m0 + (mh << 7) + (wr << 6) + (mm << 5) + (l5 << 2);
        const size_t col = ((size_t)nb << 7) + (wc << 5) + l31;
#pragma unroll
        for (int r = 0; r < 16; ++r) {
          const size_t row = rb + (r & 3) + ((r >> 2) << 3);
          const float y0 = acc[mh][0][mm][r];
          const float y1 = acc[mh][1][mm][r];
          Z[row * 8192 + col] = f2bf(gelu_tanh(y0) * y1);
        }
      }
  } else {
    float* O = (float*)outp;                          // [*, 2048]
#pragma unroll
    for (int mh = 0; mh < 2; ++mh)
#pragma unroll
      for (int g = 0; g < 2; ++g)
#pragma unroll
        for (int mm = 0; mm < 2; ++mm) {
          const size_t rb = m0 + (mh << 7) + (wr << 6) + (mm << 5) + (l5 << 2);
          const size_t col = ((size_t)nb << 8) + (g << 7) + (wc << 5) + l31;
#pragma unroll
          for (int r = 0; r < 16; ++r) {
            const size_t row = rb + (r & 3) + ((r >> 2) << 3);
            O[row * 2048 + col] = acc[mh][g][mm][r];
          }
        }
  }
}

extern "C" void kernel_launch(void* const* d_in, const int* in_sizes, int n_in,
                              void* d_out, int out_size, void* d_ws, size_t ws_size,
                              hipStream_t stream) {
  const float* x     = (const float*)d_in[0];
  const float* gamma = (const float*)d_in[1];
  const float* beta  = (const float*)d_in[2];
  const float* k1    = (const float*)d_in[3];   // [2048][2][8192] = [2048][16384]
  const float* k2    = (const float*)d_in[4];   // [8192][2048]
  float* out = (float*)d_out;

  const size_t H = 2048, I = 8192, M = 8192;
  unsigned short* k1T = (unsigned short*)d_ws;     // [16384][2048] bf16 (w0^T then w1^T)
  unsigned short* k2T = k1T + 2 * I * H;           // [2048][8192]  bf16
  unsigned short* lnb = k2T + H * I;               // [8192][2048]  bf16
  unsigned short* zb  = lnb + M * H;               // [Mc][8192]    bf16

  const size_t fixedB = (2 * I * H + H * I + M * H) * 2;  // 134.2 MB
  int nc = 1;
  while (nc < 32 && fixedB + (M / nc) * I * 2 > ws_size) nc <<= 1;

  transpose_cast_kernel<<<dim3(H / 32, (2 * I) / 32), 256, 0, stream>>>(
      k1, k1T, (int)H, (int)(2 * I));
  transpose_cast_kernel<<<dim3(I / 32, H / 32), 256, 0, stream>>>(
      k2, k2T, (int)I, (int)H);
  ln_kernel<<<dim3((unsigned)M), 256, 0, stream>>>(x, gamma, beta, lnb);

  const size_t Mc = M / nc;
  const int mC = (int)(Mc / 256);
  for (int c = 0; c < nc; ++c) {
    gemm32<2048, true><<<dim3((unsigned)(mC * 64)), 512, 0, stream>>>(
        lnb + c * Mc * H, k1T, k1T + (size_t)8192 * 2048, zb, mC);
    gemm32<8192, false><<<dim3((unsigned)(mC * 8)), 512, 0, stream>>>(
        zb, k2T, k2T + (size_t)128 * 8192, out + c * Mc * H, mC);
  }
}